// Round 3
// baseline (305.408 us; speedup 1.0000x reference)
//
#include <hip/hip_runtime.h>
#include <hip/hip_fp16.h>

// Problem constants (fixed by the reference file)
#define NN 50000     // nodes
#define NE 800000    // edges
#define HD 64        // feature dim (in and hidden)
#define NG 512       // graphs
#define NBK 196      // buckets: col >> 8, max 49999>>8 = 195
#define NBL 196      // edge blocks of 4096: ceil(NE/4096)
#define M_CNT (NBK * NBL)       // 38416 counts
#define NBS 151                 // scan blocks: ceil(M_CNT/256)
#define GEMM_BLOCKS 3125        // NN/16

// Math: with h' = dinv*h (fp16):
//   o[c]   = dinv[c] * (sum_src h'[src] + h'[c]) + b          (layer output)
//   h'next = dinv * (relu(o) @ Wnext)                          (fused GEMM)
// gemm1 writes UNSCALED fp16 h; csr_build scales it in place once dinv is
// known. Layers 2/3 GEMMs are FUSED into the gather epilogue (R19).
//
// R20 POST-MORTEM: local int arrays through helpers spill (rule #20) — named
// scalars only. R21: load-hoist (+1.5us/gather) + scan fold. Confirmed: the
// POOL dispatch (no W) times identical to fused-GEMM dispatches — the
// gather+esrc chain is the floor, epilogue is hidden.
// R22: gather was request-count-bound, not byte-bound (102 MB from L2 in
// 46.5us = 2.2 TB/s << 34.5 TB/s streaming; HBM 17%, VALU 21%, occ 65% —
// nothing saturated). Re-map lanes (pp,cc) = 4x16, 8 B/lane: each gather
// VMEM covers 4 rows (was 2), batch widens to 16 edges with 16 named-scalar
// esrc loads -> median node (deg~16) does ONE esrc->gather round (was 2),
// gather VMEM count halves. Masked tail keeps R15 clamp semantics.

struct __align__(8) h2x2 { __half2 lo, hi; };   // 4 features, one b64 load

// ---------------------------------------------------------------------------
// Pass A: per-(block,bucket) edge counts via LDS histogram (no global atomics)
// + graph node counts via sorted-batch boundary detection + zero pooled[].
__global__ __launch_bounds__(256) void bucket_count(const int* __restrict__ col,
                                                    const int* __restrict__ batch,
                                                    int* __restrict__ counts,
                                                    int* __restrict__ beg,
                                                    int* __restrict__ endx,
                                                    float* __restrict__ pooled) {
    __shared__ int hist[256];
    int tid = threadIdx.x, blk = blockIdx.x;
    hist[tid] = 0;
    __syncthreads();
    int base = blk * 4096;
#pragma unroll
    for (int k = 0; k < 16; ++k) {
        int e = base + k * 256 + tid;
        if (e < NE) atomicAdd(&hist[col[e] >> 8], 1);
    }
    int t = blk * 256 + tid;
    if (t < NG * HD) pooled[t] = 0.f;          // 50176 threads >= 32768
    if (t < NN) {
        int g = batch[t];
        if (t == 0 || batch[t - 1] != g) beg[g] = t;
        if (t == NN - 1 || batch[t + 1] != g) endx[g] = t + 1;
    }
    __syncthreads();
    if (tid < NBK) counts[tid * NBL + blk] = hist[tid];  // bucket-major
}

// ---- 2-stage exclusive scan over counts[M_CNT] ----------------------------
__global__ __launch_bounds__(256) void block_reduce(const int* __restrict__ src,
                                                    int* __restrict__ bsum) {
    __shared__ int ws[4];
    int tid = threadIdx.x, lane = tid & 63, wid = tid >> 6;
    int i = blockIdx.x * 256 + tid;
    int v = (i < M_CNT) ? src[i] : 0;
#pragma unroll
    for (int off = 32; off > 0; off >>= 1) v += __shfl_down(v, off, 64);
    if (lane == 0) ws[wid] = v;
    __syncthreads();
    if (tid == 0) bsum[blockIdx.x] = ws[0] + ws[1] + ws[2] + ws[3];
}

// block_scan (R21): computes its own bsum-prefix (reduction over raw
// per-block sums — scan_bsum kernel deleted). Wave 0 reduces
// bsum[0..blockIdx-1] while other waves do the intra-block scan.
__global__ __launch_bounds__(256) void block_scan(const int* __restrict__ src,
                                                  const int* __restrict__ bsum,
                                                  int* __restrict__ dst) {
    __shared__ int ws[4];
    __shared__ int spref;
    int tid = threadIdx.x, lane = tid & 63, wid = tid >> 6;
    int i = blockIdx.x * 256 + tid;
    int v = (i < M_CNT) ? src[i] : 0;
    int inc = v;
#pragma unroll
    for (int off = 1; off < 64; off <<= 1) {
        int t = __shfl_up(inc, off, 64);
        if (lane >= off) inc += t;
    }
    if (lane == 63) ws[wid] = inc;
    if (wid == 0) {                         // redundant prefix reduction
        int pref = 0;
        for (int base = 0; base < NBS; base += 64) {
            int k = base + lane;
            int bv = (k < NBS && k < blockIdx.x) ? bsum[k] : 0;
#pragma unroll
            for (int off = 32; off > 0; off >>= 1) bv += __shfl_down(bv, off, 64);
            pref += bv;                     // lane 0 holds the true sum
        }
        if (lane == 0) spref = pref;
    }
    __syncthreads();
    int woff = 0;
    for (int k = 0; k < wid; ++k) woff += ws[k];
    if (i < M_CNT) dst[i] = spref + woff + inc - v;
}

// ---------------------------------------------------------------------------
// Fused: blocks [0,GEMM_BLOCKS) do h16 = fp16(x @ W1) UNSCALED (scaled in
// place by csr_build); blocks [GEMM_BLOCKS, +NBL) scatter edges into packed[].
__global__ __launch_bounds__(256) void gemm1_scatter(const float* __restrict__ x,
                                                     const float* __restrict__ W1,
                                                     __half* __restrict__ h16,
                                                     const int* __restrict__ row,
                                                     const int* __restrict__ col,
                                                     const int* __restrict__ counts_ex,
                                                     unsigned* __restrict__ packed) {
    if (blockIdx.x < GEMM_BLOCKS) {
        __shared__ float Ws[64][64];   // 16 KB
        __shared__ float Is[16][64];   // 4 KB
        int t = threadIdx.x;
        for (int i = t; i < 64 * 64; i += 256) Ws[i >> 6][i & 63] = W1[i];
        int row0 = blockIdx.x * 16;
        for (int i = t; i < 16 * 64; i += 256)
            Is[i >> 6][i & 63] = x[(row0 + (i >> 6)) * HD + (i & 63)];
        __syncthreads();
        int c = t & 63, r4 = t >> 6;
        float a0 = 0.f, a1 = 0.f, a2 = 0.f, a3 = 0.f;
#pragma unroll
        for (int k = 0; k < 64; ++k) {
            float w = Ws[k][c];
            a0 += Is[r4 + 0][k] * w;
            a1 += Is[r4 + 4][k] * w;
            a2 += Is[r4 + 8][k] * w;
            a3 += Is[r4 + 12][k] * w;
        }
        h16[(row0 + r4 + 0) * HD + c] = __float2half(a0);
        h16[(row0 + r4 + 4) * HD + c] = __float2half(a1);
        h16[(row0 + r4 + 8) * HD + c] = __float2half(a2);
        h16[(row0 + r4 + 12) * HD + c] = __float2half(a3);
    } else {
        __shared__ int cur[256];
        int tid = threadIdx.x, blk = blockIdx.x - GEMM_BLOCKS;
        cur[tid] = 0;
        __syncthreads();
        int base = blk * 4096;
#pragma unroll
        for (int k = 0; k < 16; ++k) {
            int e = base + k * 256 + tid;
            if (e < NE) {
                int c = col[e], r = row[e];
                int b = c >> 8;
                int lpos = atomicAdd(&cur[b], 1);
                int pos = counts_ex[b * NBL + blk] + lpos;
                packed[pos] = (unsigned)r | ((unsigned)(c & 255) << 16);
            }
        }
    }
}

// ---------------------------------------------------------------------------
// Fused CSR build: per 256-col bucket — (1) histogram+scan -> rowptr/dinv,
// (1.5) scale h16 IN PLACE: h16 *= dinv (per row; 2nd fp16 rounding, <=1 ulp),
// (2) fill esrc via LDS cursors.
__global__ __launch_bounds__(256) void csr_build(const unsigned* __restrict__ packed,
                                                 const int* __restrict__ counts_ex,
                                                 int* __restrict__ rowptr,
                                                 float* __restrict__ dinv,
                                                 __half* __restrict__ h16,
                                                 int* __restrict__ esrc) {
    __shared__ int hist[256];
    __shared__ int ws[4];
    __shared__ int lrp[256];
    __shared__ float sdinv[256];
    int bkt = blockIdx.x, tid = threadIdx.x;
    int s = counts_ex[bkt * NBL];
    int e = (bkt == NBK - 1) ? NE : counts_ex[(bkt + 1) * NBL];
    hist[tid] = 0;
    __syncthreads();
    for (int j = s + tid; j < e; j += 256)
        atomicAdd(&hist[(packed[j] >> 16) & 255], 1);
    __syncthreads();
    int lane = tid & 63, wid = tid >> 6;
    int v = hist[tid], inc = v;
#pragma unroll
    for (int off = 1; off < 64; off <<= 1) {
        int t = __shfl_up(inc, off, 64);
        if (lane >= off) inc += t;
    }
    if (lane == 63) ws[wid] = inc;
    __syncthreads();
    int woff = 0;
    for (int k = 0; k < wid; ++k) woff += ws[k];
    int excl = s + woff + inc - v;               // exclusive scan
    int node = bkt * 256 + tid;
    float dv = rsqrtf((float)(v + 1));           // +1 self-loop
    if (node < NN) {
        rowptr[node] = excl;
        dinv[node] = dv;
    }
    if (bkt == 0 && tid == 0) rowptr[NN] = NE;
    lrp[tid] = excl;
    sdinv[tid] = dv;
    hist[tid] = 0;                               // reuse as fill cursor
    __syncthreads();
    // (1.5) scale rows of this bucket in place: h16 *= dinv
    {
        int nrows = (bkt == NBK - 1) ? (NN - 195 * 256) : 256;
        __half2* hb16 = (__half2*)(h16 + (size_t)bkt * 256 * HD);
        for (int i = tid; i < nrows * 32; i += 256) {
            float d = sdinv[i >> 5];
            float2 f = __half22float2(hb16[i]);
            hb16[i] = __floats2half2_rn(d * f.x, d * f.y);
        }
    }
    // (2) fill
    for (int j = s + tid; j < e; j += 256) {
        unsigned p = packed[j];
        int lc = (p >> 16) & 255;
        int slot = lrp[lc] + atomicAdd(&hist[lc], 1);
        esrc[slot] = (int)(p & 0xFFFF);          // NN < 65536
    }
}

// ---------------------------------------------------------------------------
// Fused gather + next-layer GEMM (R22 lane remap). ONE node per wave
// (readfirstlane -> scalar esrc stream). Lane = 16*pp + cc: pp = edge-of-quad
// (0..3), cc = 4-feature chunk (8 B = h2x2). Each gather VMEM covers 4 rows.
// 16-edge batches: 16 named-scalar esrc loads (SGPRs — NO arrays, R20
// lesson), 4 b64 gathers in flight; ONE masked batch tail (rem 1..15,
// clamp to t0 = real in-batch edge, zero-multiplied; &0xFFFF keeps pad
// reads in-bounds: 0xAAAA pad -> 43690 < NN).
// Epilogue (POOL=false): o = dinv*(acc+self)+b, then h'next[node] =
// fp16(dinv * (relu(o) @ Wnext)) — W column in VGPRs, row broadcast via
// per-wave LDS + ds_read_b128. Epilogue (POOL=true): pool atomics.
template <bool POOL>
__global__ __launch_bounds__(256) void gather_fx(const __half* __restrict__ hp,
                                                 const int* __restrict__ rowptr,
                                                 const int* __restrict__ esrc,
                                                 const float* __restrict__ dinv,
                                                 const float* __restrict__ b,
                                                 const float* __restrict__ Wnext,
                                                 __half* __restrict__ hnext,
                                                 const int* __restrict__ batch,
                                                 float* __restrict__ pooled) {
    __shared__ float rowbuf[4][64];             // 1 KB, per-wave slices
    int tid = threadIdx.x, lane = tid & 63, wid = tid >> 6;
    int pp = lane >> 4, cc = lane & 15;         // edge-of-quad, feature chunk
    int node = __builtin_amdgcn_readfirstlane(blockIdx.x * 4 + wid);
    const h2x2* hv8 = (const h2x2*)hp;

    // Independent loads FIRST (R21): overlap the rowptr->esrc scalar chain.
    float di = dinv[node];                      // wave-uniform scalar load
    h2x2 sf = hv8[node * 16 + cc];              // pre-scaled h' self row
    float2 slo = __half22float2(sf.lo);
    float2 shi = __half22float2(sf.hi);
    float4 bb = ((const float4*)b)[cc];

    float wcol[POOL ? 1 : 64];                  // W column for this lane
    if (!POOL) {
#pragma unroll
        for (int k = 0; k < 64; ++k) wcol[k] = Wnext[k * HD + lane];  // L2-hot
    }

    int s = rowptr[node], e = rowptr[node + 1]; // scalar loads
    float4 acc = {0.f, 0.f, 0.f, 0.f};
    int j = s;
    for (; j + 16 <= e; j += 16) {              // unmasked full batches
        int t0 = esrc[j + 0],  t1 = esrc[j + 1],  t2 = esrc[j + 2],  t3 = esrc[j + 3];
        int t4 = esrc[j + 4],  t5 = esrc[j + 5],  t6 = esrc[j + 6],  t7 = esrc[j + 7];
        int t8 = esrc[j + 8],  t9 = esrc[j + 9],  t10 = esrc[j + 10], t11 = esrc[j + 11];
        int t12 = esrc[j + 12], t13 = esrc[j + 13], t14 = esrc[j + 14], t15 = esrc[j + 15];
        int a0 = (pp & 2) ? ((pp & 1) ? t3 : t2) : ((pp & 1) ? t1 : t0);
        int a1 = (pp & 2) ? ((pp & 1) ? t7 : t6) : ((pp & 1) ? t5 : t4);
        int a2 = (pp & 2) ? ((pp & 1) ? t11 : t10) : ((pp & 1) ? t9 : t8);
        int a3 = (pp & 2) ? ((pp & 1) ? t15 : t14) : ((pp & 1) ? t13 : t12);
        h2x2 g0 = hv8[a0 * 16 + cc];
        h2x2 g1 = hv8[a1 * 16 + cc];
        h2x2 g2 = hv8[a2 * 16 + cc];
        h2x2 g3 = hv8[a3 * 16 + cc];
        float2 l0 = __half22float2(g0.lo), h0 = __half22float2(g0.hi);
        float2 l1 = __half22float2(g1.lo), h1 = __half22float2(g1.hi);
        float2 l2 = __half22float2(g2.lo), h2 = __half22float2(g2.hi);
        float2 l3 = __half22float2(g3.lo), h3 = __half22float2(g3.hi);
        acc.x += (l0.x + l1.x) + (l2.x + l3.x);
        acc.y += (l0.y + l1.y) + (l2.y + l3.y);
        acc.z += (h0.x + h1.x) + (h2.x + h3.x);
        acc.w += (h0.y + h1.y) + (h2.y + h3.y);
    }
    if (j < e) {                                // ONE masked batch (rem 1..15)
        // overrun reads stay in allocated memory (esrc padded +64); &0xFFFF
        // keeps row index in-bounds (0xAAAA pad -> 43690 < NN); zero-masked.
        int t0 = esrc[j + 0] & 0xFFFF,  t1 = esrc[j + 1] & 0xFFFF;
        int t2 = esrc[j + 2] & 0xFFFF,  t3 = esrc[j + 3] & 0xFFFF;
        int t4 = esrc[j + 4] & 0xFFFF,  t5 = esrc[j + 5] & 0xFFFF;
        int t6 = esrc[j + 6] & 0xFFFF,  t7 = esrc[j + 7] & 0xFFFF;
        int t8 = esrc[j + 8] & 0xFFFF,  t9 = esrc[j + 9] & 0xFFFF;
        int t10 = esrc[j + 10] & 0xFFFF, t11 = esrc[j + 11] & 0xFFFF;
        int t12 = esrc[j + 12] & 0xFFFF, t13 = esrc[j + 13] & 0xFFFF;
        int t14 = esrc[j + 14] & 0xFFFF, t15 = esrc[j + 15] & 0xFFFF;
        int i0 = j + 0 + pp, i1 = j + 4 + pp, i2 = j + 8 + pp, i3 = j + 12 + pp;
        int a0 = (pp & 2) ? ((pp & 1) ? t3 : t2) : ((pp & 1) ? t1 : t0);
        int a1 = (pp & 2) ? ((pp & 1) ? t7 : t6) : ((pp & 1) ? t5 : t4);
        int a2 = (pp & 2) ? ((pp & 1) ? t11 : t10) : ((pp & 1) ? t9 : t8);
        int a3 = (pp & 2) ? ((pp & 1) ? t15 : t14) : ((pp & 1) ? t13 : t12);
        a0 = (i0 < e) ? a0 : t0;                // t0 = real edge (j < e)
        a1 = (i1 < e) ? a1 : t0;
        a2 = (i2 < e) ? a2 : t0;
        a3 = (i3 < e) ? a3 : t0;
        float m0 = (i0 < e) ? 1.f : 0.f;
        float m1 = (i1 < e) ? 1.f : 0.f;
        float m2 = (i2 < e) ? 1.f : 0.f;
        float m3 = (i3 < e) ? 1.f : 0.f;
        h2x2 g0 = hv8[a0 * 16 + cc];
        h2x2 g1 = hv8[a1 * 16 + cc];
        h2x2 g2 = hv8[a2 * 16 + cc];
        h2x2 g3 = hv8[a3 * 16 + cc];
        float2 l0 = __half22float2(g0.lo), h0 = __half22float2(g0.hi);
        float2 l1 = __half22float2(g1.lo), h1 = __half22float2(g1.hi);
        float2 l2 = __half22float2(g2.lo), h2 = __half22float2(g2.hi);
        float2 l3 = __half22float2(g3.lo), h3 = __half22float2(g3.hi);
        acc.x += m0 * l0.x + m1 * l1.x + m2 * l2.x + m3 * l3.x;
        acc.y += m0 * l0.y + m1 * l1.y + m2 * l2.y + m3 * l3.y;
        acc.z += m0 * h0.x + m1 * h1.x + m2 * h2.x + m3 * h3.x;
        acc.w += m0 * h0.y + m1 * h1.y + m2 * h2.y + m3 * h3.y;
    }
    // combine the four edge-quad partials (lanes with same cc across pp)
    acc.x += __shfl_xor(acc.x, 16, 64);
    acc.y += __shfl_xor(acc.y, 16, 64);
    acc.z += __shfl_xor(acc.z, 16, 64);
    acc.w += __shfl_xor(acc.w, 16, 64);
    acc.x += __shfl_xor(acc.x, 32, 64);
    acc.y += __shfl_xor(acc.y, 32, 64);
    acc.z += __shfl_xor(acc.z, 32, 64);
    acc.w += __shfl_xor(acc.w, 32, 64);

    if (POOL) {
        if (pp == 0) {
            float vx = di * (acc.x + slo.x) + bb.x;
            float vy = di * (acc.y + slo.y) + bb.y;
            float vz = di * (acc.z + shi.x) + bb.z;
            float vw = di * (acc.w + shi.y) + bb.w;
            int g = batch[node];
            atomicAdd(&pooled[g * HD + 4 * cc + 0], vx);
            atomicAdd(&pooled[g * HD + 4 * cc + 1], vy);
            atomicAdd(&pooled[g * HD + 4 * cc + 2], vz);
            atomicAdd(&pooled[g * HD + 4 * cc + 3], vw);
        }
    } else {
        if (pp == 0) {                          // o = dinv*(acc+self)+b; relu
            float4 o;
            o.x = fmaxf(di * (acc.x + slo.x) + bb.x, 0.f);
            o.y = fmaxf(di * (acc.y + slo.y) + bb.y, 0.f);
            o.z = fmaxf(di * (acc.z + shi.x) + bb.z, 0.f);
            o.w = fmaxf(di * (acc.w + shi.y) + bb.w, 0.f);
            *(float4*)&rowbuf[wid][4 * cc] = o;
        }
        // same-wave LDS write->read; compiler inserts lgkmcnt wait. No cross-
        // wave hazard: rowbuf slice is private to this wave.
        float outc = 0.f;
        const float4* rb4 = (const float4*)&rowbuf[wid][0];
#pragma unroll
        for (int jj = 0; jj < 16; ++jj) {       // 16 broadcast b128 reads
            float4 r = rb4[jj];
            outc += r.x * wcol[4 * jj + 0] + r.y * wcol[4 * jj + 1]
                  + r.z * wcol[4 * jj + 2] + r.w * wcol[4 * jj + 3];
        }
        hnext[(size_t)node * HD + lane] = __float2half(di * outc);
    }
}

// out[g] = (pooled[g,:]/max(cnt,1)) . lin_W + lin_b   — one wave per graph
__global__ __launch_bounds__(64) void final_kernel(const float* __restrict__ pooled,
                                                   const int* __restrict__ beg,
                                                   const int* __restrict__ endx,
                                                   const float* __restrict__ lin_W,
                                                   const float* __restrict__ lin_b,
                                                   float* __restrict__ out) {
    int g = blockIdx.x, d = threadIdx.x;
    float cnt = (float)(endx[g] - beg[g]);
    float v = pooled[g * HD + d] / fmaxf(cnt, 1.f) * lin_W[d];
#pragma unroll
    for (int off = 32; off > 0; off >>= 1) v += __shfl_down(v, off, 64);
    if (d == 0) out[g] = v + lin_b[0];
}

// ---------------------------------------------------------------------------
extern "C" void kernel_launch(void* const* d_in, const int* in_sizes, int n_in,
                              void* d_out, int out_size, void* d_ws, size_t ws_size,
                              hipStream_t stream) {
    const float* x     = (const float*)d_in[0];
    const float* W1    = (const float*)d_in[1];
    const float* b1    = (const float*)d_in[2];
    const float* W2    = (const float*)d_in[3];
    const float* b2    = (const float*)d_in[4];
    const float* W3    = (const float*)d_in[5];
    const float* b3    = (const float*)d_in[6];
    const float* lin_W = (const float*)d_in[7];
    const float* lin_b = (const float*)d_in[8];
    const int* edge_index = (const int*)d_in[9];   // [2, NE]: row then col
    const int* batch      = (const int*)d_in[10];
    const int* row = edge_index;
    const int* col = edge_index + NE;
    float* out = (float*)d_out;

    // workspace layout (4B units):
    // [h16a NN*HD half][h16b NN*HD half][esrc NE+64][packed NE]
    // [counts M][counts_ex M][rowptr NN+2][dinv NN][bsum 256]
    // [pooled NG*HD][beg NG][endx NG]        total ~20 MB
    __half*   h16a      = (__half*)d_ws;
    __half*   h16b      = h16a + (size_t)NN * HD;
    int*      esrc      = (int*)(h16b + (size_t)NN * HD);
    unsigned* packed    = (unsigned*)(esrc + NE + 64);
    int*      counts    = (int*)(packed + NE);
    int*      counts_ex = counts + M_CNT;
    int*      rowptr    = counts_ex + M_CNT;
    float*    dinv      = (float*)(rowptr + NN + 2);
    int*      bsum      = (int*)(dinv + NN);
    float*    pooled    = (float*)(bsum + 256);
    int*      beg       = (int*)(pooled + NG * HD);
    int*      endx      = beg + NG;

    // CSR build: count(+zero pooled) -> reduce -> (scan w/ folded prefix)
    //            -> (scatter fused w/ gemm1) -> fused rowptr + scale + fill
    bucket_count<<<NBL, 256, 0, stream>>>(col, batch, counts, beg, endx, pooled);
    block_reduce<<<NBS, 256, 0, stream>>>(counts, bsum);
    block_scan<<<NBS, 256, 0, stream>>>(counts, bsum, counts_ex);
    gemm1_scatter<<<GEMM_BLOCKS + NBL, 256, 0, stream>>>(x, W1, h16a, row, col,
                                                         counts_ex, packed);
    csr_build<<<NBK, 256, 0, stream>>>(packed, counts_ex, rowptr, dinv,
                                       h16a, esrc);

    const int GB = NN / 4;  // gather blocks: 4 nodes (waves) each

    // Layer 1 aggregate + fused GEMM2: h16a(=h1') -> h16b(=h2')
    gather_fx<false><<<GB, 256, 0, stream>>>(h16a, rowptr, esrc, dinv, b1, W2,
                                             h16b, batch, pooled);
    // Layer 2 aggregate + fused GEMM3: h16b(=h2') -> h16a(=h3')
    gather_fx<false><<<GB, 256, 0, stream>>>(h16b, rowptr, esrc, dinv, b2, W3,
                                             h16a, batch, pooled);
    // Layer 3 aggregate -> pooled (fused)
    gather_fx<true><<<GB, 256, 0, stream>>>(h16a, rowptr, esrc, dinv, b3, nullptr,
                                            nullptr, batch, pooled);

    final_kernel<<<NG, 64, 0, stream>>>(pooled, beg, endx, lin_W, lin_b, out);
}

// Round 4
// 255.334 us; speedup vs baseline: 1.1961x; 1.1961x over previous
//
#include <hip/hip_runtime.h>
#include <hip/hip_fp16.h>

// Problem constants (fixed by the reference file)
#define NN 50000     // nodes
#define NE 800000    // edges
#define HD 64        // feature dim (in and hidden)
#define NG 512       // graphs
#define NBK 196      // buckets: col >> 8, max 49999>>8 = 195
#define NBL 196      // edge blocks of 4096: ceil(NE/4096)
#define M_CNT (NBK * NBL)       // 38416 counts
#define NBS 151                 // scan blocks: ceil(M_CNT/256)
#define GEMM_BLOCKS 3125        // NN/16

// Math: with h' = dinv*h (fp16):
//   o[c]   = dinv[c] * (sum_src h'[src] + h'[c]) + b          (layer output)
//   h'next = dinv * (relu(o) @ Wnext)                          (fused GEMM)
// gemm1 writes UNSCALED fp16 h; csr_build scales it in place once dinv is
// known. Layers 2/3 GEMMs are FUSED into the gather epilogue (R19).
// Gather body is R15/R21's proven shape (46.5 µs; ~12 variants tried):
// node-per-wave, scalar esrc stream, unmasked 8-edge batches + ONE masked
// batch, independent loads hoisted. DO NOT TOUCH:
//  - R20: int t[32] preload -> scratch spill (+25.6MB writes), 2x slower.
//  - R22: h2x2 8B-aggregate loads -> 8B/thread scratch (+25.6MB writes),
//    2x slower. FETCH 35MB ~= compulsory floor (each XCD reads ~2 rows/line
//    of the 6.4MB h16) -> gather is at its random-fabric roofline.
// R23: gemm1's GEMM half was LDS-issue-bound (5 scalar ds_read_b32 per
// 4 FMA). W1 column now in 64 VGPRs (proven epilogue pattern); Is rows via
// wave-uniform broadcast float4 (lanes share r4 -> same addr -> free).
// Same k-ascending accumulation order -> bit-identical output.

// ---------------------------------------------------------------------------
// Pass A: per-(block,bucket) edge counts via LDS histogram (no global atomics)
// + graph node counts via sorted-batch boundary detection + zero pooled[].
__global__ __launch_bounds__(256) void bucket_count(const int* __restrict__ col,
                                                    const int* __restrict__ batch,
                                                    int* __restrict__ counts,
                                                    int* __restrict__ beg,
                                                    int* __restrict__ endx,
                                                    float* __restrict__ pooled) {
    __shared__ int hist[256];
    int tid = threadIdx.x, blk = blockIdx.x;
    hist[tid] = 0;
    __syncthreads();
    int base = blk * 4096;
#pragma unroll
    for (int k = 0; k < 16; ++k) {
        int e = base + k * 256 + tid;
        if (e < NE) atomicAdd(&hist[col[e] >> 8], 1);
    }
    int t = blk * 256 + tid;
    if (t < NG * HD) pooled[t] = 0.f;          // 50176 threads >= 32768
    if (t < NN) {
        int g = batch[t];
        if (t == 0 || batch[t - 1] != g) beg[g] = t;
        if (t == NN - 1 || batch[t + 1] != g) endx[g] = t + 1;
    }
    __syncthreads();
    if (tid < NBK) counts[tid * NBL + blk] = hist[tid];  // bucket-major
}

// ---- 2-stage exclusive scan over counts[M_CNT] ----------------------------
__global__ __launch_bounds__(256) void block_reduce(const int* __restrict__ src,
                                                    int* __restrict__ bsum) {
    __shared__ int ws[4];
    int tid = threadIdx.x, lane = tid & 63, wid = tid >> 6;
    int i = blockIdx.x * 256 + tid;
    int v = (i < M_CNT) ? src[i] : 0;
#pragma unroll
    for (int off = 32; off > 0; off >>= 1) v += __shfl_down(v, off, 64);
    if (lane == 0) ws[wid] = v;
    __syncthreads();
    if (tid == 0) bsum[blockIdx.x] = ws[0] + ws[1] + ws[2] + ws[3];
}

// block_scan (R21): computes its own bsum-prefix (reduction over raw
// per-block sums — scan_bsum kernel deleted). Wave 0 reduces
// bsum[0..blockIdx-1] while other waves do the intra-block scan.
__global__ __launch_bounds__(256) void block_scan(const int* __restrict__ src,
                                                  const int* __restrict__ bsum,
                                                  int* __restrict__ dst) {
    __shared__ int ws[4];
    __shared__ int spref;
    int tid = threadIdx.x, lane = tid & 63, wid = tid >> 6;
    int i = blockIdx.x * 256 + tid;
    int v = (i < M_CNT) ? src[i] : 0;
    int inc = v;
#pragma unroll
    for (int off = 1; off < 64; off <<= 1) {
        int t = __shfl_up(inc, off, 64);
        if (lane >= off) inc += t;
    }
    if (lane == 63) ws[wid] = inc;
    if (wid == 0) {                         // redundant prefix reduction
        int pref = 0;
        for (int base = 0; base < NBS; base += 64) {
            int k = base + lane;
            int bv = (k < NBS && k < blockIdx.x) ? bsum[k] : 0;
#pragma unroll
            for (int off = 32; off > 0; off >>= 1) bv += __shfl_down(bv, off, 64);
            pref += bv;                     // lane 0 holds the true sum
        }
        if (lane == 0) spref = pref;
    }
    __syncthreads();
    int woff = 0;
    for (int k = 0; k < wid; ++k) woff += ws[k];
    if (i < M_CNT) dst[i] = spref + woff + inc - v;
}

// ---------------------------------------------------------------------------
// Fused: blocks [0,GEMM_BLOCKS) do h16 = fp16(x @ W1) UNSCALED (scaled in
// place by csr_build); blocks [GEMM_BLOCKS, +NBL) scatter edges into packed[].
// R23 GEMM half: W1 column in VGPRs (64 coalesced dword loads, L2-hot, issued
// before staging so latency overlaps); Is rows staged in LDS (4 KB) and read
// as wave-uniform BROADCAST float4 (tid>>6 = r4 is wave-uniform -> all 64
// lanes same address -> conflict-free). k-ascending FMA order preserved.
__global__ __launch_bounds__(256) void gemm1_scatter(const float* __restrict__ x,
                                                     const float* __restrict__ W1,
                                                     __half* __restrict__ h16,
                                                     const int* __restrict__ row,
                                                     const int* __restrict__ col,
                                                     const int* __restrict__ counts_ex,
                                                     unsigned* __restrict__ packed) {
    if (blockIdx.x < GEMM_BLOCKS) {
        __shared__ float Is[16][64];   // 4 KB
        int t = threadIdx.x;
        int c = t & 63, r4 = t >> 6;
        float wcol[64];                // W1 column c, L2-hot (16 KB total)
#pragma unroll
        for (int k = 0; k < 64; ++k) wcol[k] = W1[k * HD + c];
        int row0 = blockIdx.x * 16;
        for (int i = t; i < 16 * 64; i += 256)
            Is[i >> 6][i & 63] = x[(row0 + (i >> 6)) * HD + (i & 63)];
        __syncthreads();
        float a0 = 0.f, a1 = 0.f, a2 = 0.f, a3 = 0.f;
        const float4* i0p = (const float4*)&Is[r4 + 0][0];
        const float4* i1p = (const float4*)&Is[r4 + 4][0];
        const float4* i2p = (const float4*)&Is[r4 + 8][0];
        const float4* i3p = (const float4*)&Is[r4 + 12][0];
#pragma unroll
        for (int q = 0; q < 16; ++q) {  // k = 4q..4q+3, ascending (bit-exact)
            float4 i0 = i0p[q], i1 = i1p[q], i2 = i2p[q], i3 = i3p[q];
            float w0 = wcol[4 * q + 0], w1 = wcol[4 * q + 1];
            float w2 = wcol[4 * q + 2], w3 = wcol[4 * q + 3];
            a0 += i0.x * w0; a0 += i0.y * w1; a0 += i0.z * w2; a0 += i0.w * w3;
            a1 += i1.x * w0; a1 += i1.y * w1; a1 += i1.z * w2; a1 += i1.w * w3;
            a2 += i2.x * w0; a2 += i2.y * w1; a2 += i2.z * w2; a2 += i2.w * w3;
            a3 += i3.x * w0; a3 += i3.y * w1; a3 += i3.z * w2; a3 += i3.w * w3;
        }
        h16[(row0 + r4 + 0) * HD + c] = __float2half(a0);
        h16[(row0 + r4 + 4) * HD + c] = __float2half(a1);
        h16[(row0 + r4 + 8) * HD + c] = __float2half(a2);
        h16[(row0 + r4 + 12) * HD + c] = __float2half(a3);
    } else {
        __shared__ int cur[256];
        int tid = threadIdx.x, blk = blockIdx.x - GEMM_BLOCKS;
        cur[tid] = 0;
        __syncthreads();
        int base = blk * 4096;
#pragma unroll
        for (int k = 0; k < 16; ++k) {
            int e = base + k * 256 + tid;
            if (e < NE) {
                int c = col[e], r = row[e];
                int b = c >> 8;
                int lpos = atomicAdd(&cur[b], 1);
                int pos = counts_ex[b * NBL + blk] + lpos;
                packed[pos] = (unsigned)r | ((unsigned)(c & 255) << 16);
            }
        }
    }
}

// ---------------------------------------------------------------------------
// Fused CSR build: per 256-col bucket — (1) histogram+scan -> rowptr/dinv,
// (1.5) scale h16 IN PLACE: h16 *= dinv (per row; 2nd fp16 rounding, <=1 ulp),
// (2) fill esrc via LDS cursors.
__global__ __launch_bounds__(256) void csr_build(const unsigned* __restrict__ packed,
                                                 const int* __restrict__ counts_ex,
                                                 int* __restrict__ rowptr,
                                                 float* __restrict__ dinv,
                                                 __half* __restrict__ h16,
                                                 int* __restrict__ esrc) {
    __shared__ int hist[256];
    __shared__ int ws[4];
    __shared__ int lrp[256];
    __shared__ float sdinv[256];
    int bkt = blockIdx.x, tid = threadIdx.x;
    int s = counts_ex[bkt * NBL];
    int e = (bkt == NBK - 1) ? NE : counts_ex[(bkt + 1) * NBL];
    hist[tid] = 0;
    __syncthreads();
    for (int j = s + tid; j < e; j += 256)
        atomicAdd(&hist[(packed[j] >> 16) & 255], 1);
    __syncthreads();
    int lane = tid & 63, wid = tid >> 6;
    int v = hist[tid], inc = v;
#pragma unroll
    for (int off = 1; off < 64; off <<= 1) {
        int t = __shfl_up(inc, off, 64);
        if (lane >= off) inc += t;
    }
    if (lane == 63) ws[wid] = inc;
    __syncthreads();
    int woff = 0;
    for (int k = 0; k < wid; ++k) woff += ws[k];
    int excl = s + woff + inc - v;               // exclusive scan
    int node = bkt * 256 + tid;
    float dv = rsqrtf((float)(v + 1));           // +1 self-loop
    if (node < NN) {
        rowptr[node] = excl;
        dinv[node] = dv;
    }
    if (bkt == 0 && tid == 0) rowptr[NN] = NE;
    lrp[tid] = excl;
    sdinv[tid] = dv;
    hist[tid] = 0;                               // reuse as fill cursor
    __syncthreads();
    // (1.5) scale rows of this bucket in place: h16 *= dinv
    {
        int nrows = (bkt == NBK - 1) ? (NN - 195 * 256) : 256;
        __half2* hb16 = (__half2*)(h16 + (size_t)bkt * 256 * HD);
        for (int i = tid; i < nrows * 32; i += 256) {
            float d = sdinv[i >> 5];
            float2 f = __half22float2(hb16[i]);
            hb16[i] = __floats2half2_rn(d * f.x, d * f.y);
        }
    }
    // (2) fill
    for (int j = s + tid; j < e; j += 256) {
        unsigned p = packed[j];
        int lc = (p >> 16) & 255;
        int slot = lrp[lc] + atomicAdd(&hist[lc], 1);
        esrc[slot] = (int)(p & 0xFFFF);          // NN < 65536
    }
}

// ---------------------------------------------------------------------------
// Fused gather + next-layer GEMM (R19 body + R21 load-hoist — bench-proven
// 46.5 µs, at its random-fabric roofline; see header). ONE node per wave
// (readfirstlane -> scalar esrc stream). NAMED SCALARS ONLY.
// Epilogue (POOL=false): o = dinv*(acc+self)+b, then h'next[node] =
// fp16(dinv * (relu(o) @ Wnext)) — W column in VGPRs, row broadcast via
// per-wave LDS + ds_read_b128. Epilogue (POOL=true): pool atomics.
template <bool POOL>
__global__ __launch_bounds__(256) void gather_fx(const __half* __restrict__ hp,
                                                 const int* __restrict__ rowptr,
                                                 const int* __restrict__ esrc,
                                                 const float* __restrict__ dinv,
                                                 const float* __restrict__ b,
                                                 const float* __restrict__ Wnext,
                                                 __half* __restrict__ hnext,
                                                 const int* __restrict__ batch,
                                                 float* __restrict__ pooled) {
    __shared__ float rowbuf[4][64];             // 1 KB, per-wave slices
    int tid = threadIdx.x, lane = tid & 63, wid = tid >> 6;
    int p = lane >> 5, c = lane & 31;           // edge-of-pair, half2 channel
    int node = __builtin_amdgcn_readfirstlane(blockIdx.x * 4 + wid);
    const __half2* hv = (const __half2*)hp;

    // Independent loads FIRST (R21): overlap the rowptr->esrc scalar chain.
    float di = dinv[node];                      // wave-uniform scalar load
    float2 self = __half22float2(hv[node * 32 + c]);   // pre-scaled h'
    float2 bb = ((const float2*)b)[c];

    float wcol[POOL ? 1 : 64];                  // W column for this lane
    if (!POOL) {
#pragma unroll
        for (int k = 0; k < 64; ++k) wcol[k] = Wnext[k * HD + lane];  // L2-hot
    }

    int s = rowptr[node], e = rowptr[node + 1];     // scalar loads
    float2 acc = {0.f, 0.f};
    int j = s;
    for (; j + 8 <= e; j += 8) {                // unmasked full batches
        int t0 = esrc[j + 0], t1 = esrc[j + 1], t2 = esrc[j + 2], t3 = esrc[j + 3];
        int t4 = esrc[j + 4], t5 = esrc[j + 5], t6 = esrc[j + 6], t7 = esrc[j + 7];
        int a0 = p ? t1 : t0;
        int a1 = p ? t3 : t2;
        int a2 = p ? t5 : t4;
        int a3 = p ? t7 : t6;
        float2 f0 = __half22float2(hv[a0 * 32 + c]);
        float2 f1 = __half22float2(hv[a1 * 32 + c]);
        float2 f2 = __half22float2(hv[a2 * 32 + c]);
        float2 f3 = __half22float2(hv[a3 * 32 + c]);
        acc.x += (f0.x + f1.x) + (f2.x + f3.x);
        acc.y += (f0.y + f1.y) + (f2.y + f3.y);
    }
    if (j < e) {                                // ONE masked batch (rem 1..7)
        // overrun reads stay in allocated memory (esrc padded +64); &0xFFFF
        // keeps row index in-bounds (0xAAAA pad -> 43690 < NN); zero-masked.
        int t0 = esrc[j + 0] & 0xFFFF, t1 = esrc[j + 1] & 0xFFFF;
        int t2 = esrc[j + 2] & 0xFFFF, t3 = esrc[j + 3] & 0xFFFF;
        int t4 = esrc[j + 4] & 0xFFFF, t5 = esrc[j + 5] & 0xFFFF;
        int t6 = esrc[j + 6] & 0xFFFF, t7 = esrc[j + 7] & 0xFFFF;
        int i0 = j + p, i1 = j + 2 + p, i2 = j + 4 + p, i3 = j + 6 + p;
        int a0 = p ? t1 : t0;
        int a1 = p ? t3 : t2;
        int a2 = p ? t5 : t4;
        int a3 = p ? t7 : t6;
        a0 = (i0 < e) ? a0 : t0;
        a1 = (i1 < e) ? a1 : t0;
        a2 = (i2 < e) ? a2 : t0;
        a3 = (i3 < e) ? a3 : t0;
        float m0 = (i0 < e) ? 1.f : 0.f;
        float m1 = (i1 < e) ? 1.f : 0.f;
        float m2 = (i2 < e) ? 1.f : 0.f;
        float m3 = (i3 < e) ? 1.f : 0.f;
        float2 f0 = __half22float2(hv[a0 * 32 + c]);
        float2 f1 = __half22float2(hv[a1 * 32 + c]);
        float2 f2 = __half22float2(hv[a2 * 32 + c]);
        float2 f3 = __half22float2(hv[a3 * 32 + c]);
        acc.x += m0 * f0.x + m1 * f1.x + m2 * f2.x + m3 * f3.x;
        acc.y += m0 * f0.y + m1 * f1.y + m2 * f2.y + m3 * f3.y;
    }
    // combine the two edge-pair partials (lane L ^ 32 holds same channel)
    acc.x += __shfl_xor(acc.x, 32, 64);
    acc.y += __shfl_xor(acc.y, 32, 64);

    if (POOL) {
        if (p == 0) {
            float vx = di * (acc.x + self.x) + bb.x;
            float vy = di * (acc.y + self.y) + bb.y;
            int g = batch[node];
            atomicAdd(&pooled[g * HD + 2 * c], vx);
            atomicAdd(&pooled[g * HD + 2 * c + 1], vy);
        }
    } else {
        if (p == 0) {                           // o = dinv*(acc+self)+b; relu
            rowbuf[wid][2 * c]     = fmaxf(di * (acc.x + self.x) + bb.x, 0.f);
            rowbuf[wid][2 * c + 1] = fmaxf(di * (acc.y + self.y) + bb.y, 0.f);
        }
        // same-wave LDS write->read; compiler inserts lgkmcnt wait. No cross-
        // wave hazard: rowbuf slice is private to this wave.
        float outc = 0.f;
        const float4* rb4 = (const float4*)&rowbuf[wid][0];
#pragma unroll
        for (int jj = 0; jj < 16; ++jj) {       // 16 broadcast b128 reads
            float4 r = rb4[jj];
            outc += r.x * wcol[4 * jj + 0] + r.y * wcol[4 * jj + 1]
                  + r.z * wcol[4 * jj + 2] + r.w * wcol[4 * jj + 3];
        }
        hnext[(size_t)node * HD + lane] = __float2half(di * outc);
    }
}

// out[g] = (pooled[g,:]/max(cnt,1)) . lin_W + lin_b   — one wave per graph
__global__ __launch_bounds__(64) void final_kernel(const float* __restrict__ pooled,
                                                   const int* __restrict__ beg,
                                                   const int* __restrict__ endx,
                                                   const float* __restrict__ lin_W,
                                                   const float* __restrict__ lin_b,
                                                   float* __restrict__ out) {
    int g = blockIdx.x, d = threadIdx.x;
    float cnt = (float)(endx[g] - beg[g]);
    float v = pooled[g * HD + d] / fmaxf(cnt, 1.f) * lin_W[d];
#pragma unroll
    for (int off = 32; off > 0; off >>= 1) v += __shfl_down(v, off, 64);
    if (d == 0) out[g] = v + lin_b[0];
}

// ---------------------------------------------------------------------------
extern "C" void kernel_launch(void* const* d_in, const int* in_sizes, int n_in,
                              void* d_out, int out_size, void* d_ws, size_t ws_size,
                              hipStream_t stream) {
    const float* x     = (const float*)d_in[0];
    const float* W1    = (const float*)d_in[1];
    const float* b1    = (const float*)d_in[2];
    const float* W2    = (const float*)d_in[3];
    const float* b2    = (const float*)d_in[4];
    const float* W3    = (const float*)d_in[5];
    const float* b3    = (const float*)d_in[6];
    const float* lin_W = (const float*)d_in[7];
    const float* lin_b = (const float*)d_in[8];
    const int* edge_index = (const int*)d_in[9];   // [2, NE]: row then col
    const int* batch      = (const int*)d_in[10];
    const int* row = edge_index;
    const int* col = edge_index + NE;
    float* out = (float*)d_out;

    // workspace layout (4B units):
    // [h16a NN*HD half][h16b NN*HD half][esrc NE+64][packed NE]
    // [counts M][counts_ex M][rowptr NN+2][dinv NN][bsum 256]
    // [pooled NG*HD][beg NG][endx NG]        total ~20 MB
    __half*   h16a      = (__half*)d_ws;
    __half*   h16b      = h16a + (size_t)NN * HD;
    int*      esrc      = (int*)(h16b + (size_t)NN * HD);
    unsigned* packed    = (unsigned*)(esrc + NE + 64);
    int*      counts    = (int*)(packed + NE);
    int*      counts_ex = counts + M_CNT;
    int*      rowptr    = counts_ex + M_CNT;
    float*    dinv      = (float*)(rowptr + NN + 2);
    int*      bsum      = (int*)(dinv + NN);
    float*    pooled    = (float*)(bsum + 256);
    int*      beg       = (int*)(pooled + NG * HD);
    int*      endx      = beg + NG;

    // CSR build: count(+zero pooled) -> reduce -> (scan w/ folded prefix)
    //            -> (scatter fused w/ gemm1) -> fused rowptr + scale + fill
    bucket_count<<<NBL, 256, 0, stream>>>(col, batch, counts, beg, endx, pooled);
    block_reduce<<<NBS, 256, 0, stream>>>(counts, bsum);
    block_scan<<<NBS, 256, 0, stream>>>(counts, bsum, counts_ex);
    gemm1_scatter<<<GEMM_BLOCKS + NBL, 256, 0, stream>>>(x, W1, h16a, row, col,
                                                         counts_ex, packed);
    csr_build<<<NBK, 256, 0, stream>>>(packed, counts_ex, rowptr, dinv,
                                       h16a, esrc);

    const int GB = NN / 4;  // gather blocks: 4 nodes (waves) each

    // Layer 1 aggregate + fused GEMM2: h16a(=h1') -> h16b(=h2')
    gather_fx<false><<<GB, 256, 0, stream>>>(h16a, rowptr, esrc, dinv, b1, W2,
                                             h16b, batch, pooled);
    // Layer 2 aggregate + fused GEMM3: h16b(=h2') -> h16a(=h3')
    gather_fx<false><<<GB, 256, 0, stream>>>(h16b, rowptr, esrc, dinv, b2, W3,
                                             h16a, batch, pooled);
    // Layer 3 aggregate -> pooled (fused)
    gather_fx<true><<<GB, 256, 0, stream>>>(h16a, rowptr, esrc, dinv, b3, nullptr,
                                            nullptr, batch, pooled);

    final_kernel<<<NG, 64, 0, stream>>>(pooled, beg, endx, lin_W, lin_b, out);
}